// Round 5
// baseline (646.849 us; speedup 1.0000x reference)
//
#include <hip/hip_runtime.h>
#include <hip/hip_bf16.h>

#define N_NODES  50000
#define N_GRAPHS 128
#define N_EDGES  800000
#define HID      128
#define SCAN_BS  256
#define SCAN_NB  ((N_NODES + SCAN_BS - 1) / SCAN_BS)

typedef __attribute__((ext_vector_type(8))) short short8;
typedef __attribute__((ext_vector_type(4))) float f32x4;

static __device__ __forceinline__ ushort f2bf(float f){
  __hip_bfloat16 h = __float2bfloat16(f);
  return *reinterpret_cast<ushort*>(&h);
}
static __device__ __forceinline__ float bf_lo(uint pk){ return __uint_as_float(pk << 16); }
static __device__ __forceinline__ float bf_hi(uint pk){ return __uint_as_float(pk & 0xffff0000u); }

// ---------------- graph preprocessing ----------------

__global__ void k_count(const int* __restrict__ dst, int* __restrict__ deg, int E){
  int i = blockIdx.x*blockDim.x + threadIdx.x;
  if (i < E) atomicAdd(&deg[dst[i]], 1);
}

__global__ void k_dinv(const int* __restrict__ deg, float* __restrict__ dinv, int N){
  int i = blockIdx.x*blockDim.x + threadIdx.x;
  if (i < N) dinv[i] = rsqrtf((float)(deg[i] + 1));   // +1 self loop
}

__global__ void k_scan1(const int* __restrict__ deg, int* __restrict__ lexc,
                        int* __restrict__ bsum, int N){
  __shared__ int s[SCAN_BS];
  int t = threadIdx.x, i = blockIdx.x*SCAN_BS + t;
  int v = (i < N) ? deg[i] : 0;
  s[t] = v;
  __syncthreads();
  int acc = v;
  for (int d = 1; d < SCAN_BS; d <<= 1){
    int u = (t >= d) ? s[t-d] : 0;
    __syncthreads();
    acc += u; s[t] = acc;
    __syncthreads();
  }
  if (i < N) lexc[i] = acc - v;
  if (t == SCAN_BS-1) bsum[blockIdx.x] = acc;
}

__global__ void k_scan2(const int* __restrict__ bsum, int* __restrict__ boff,
                        int* __restrict__ row_start){
  __shared__ int s[SCAN_NB];
  int t = threadIdx.x;
  int v = (t < SCAN_NB) ? bsum[t] : 0;
  if (t < SCAN_NB) s[t] = v;
  __syncthreads();
  int acc = v;
  for (int d = 1; d < SCAN_NB; d <<= 1){
    int u = (t >= d && t - d < SCAN_NB) ? s[t-d] : 0;
    __syncthreads();
    if (t < SCAN_NB){ acc += u; s[t] = acc; }
    __syncthreads();
  }
  if (t < SCAN_NB) boff[t] = acc - v;
  if (t == SCAN_NB-1) row_start[N_NODES] = acc;
}

__global__ void k_scan3(const int* __restrict__ lexc, const int* __restrict__ boff,
                        int* __restrict__ row_start, int N){
  int i = blockIdx.x*blockDim.x + threadIdx.x;
  if (i < N) row_start[i] = lexc[i] + boff[i >> 8];
}

__global__ void k_scatter(const int* __restrict__ src, const int* __restrict__ dst,
                          const int* __restrict__ row_start, int* __restrict__ cursor,
                          int* __restrict__ csr_src, int E){
  int i = blockIdx.x*blockDim.x + threadIdx.x;
  if (i >= E) return;
  int d = dst[i];
  int pos = row_start[d] + atomicAdd(&cursor[d], 1);
  csr_src[pos] = src[i];
}

// transpose + bf16-convert weight: W[K][N] -> Wt[N][K]
__global__ void k_wt(const float* __restrict__ W, ushort* __restrict__ Wt, int K){
  int idx = blockIdx.x*blockDim.x + threadIdx.x;
  if (idx >= K*HID) return;
  int k = idx >> 7, n = idx & 127;
  Wt[n*K + k] = f2bf(W[idx]);
}

// ---------------- bf16 MFMA GEMM: Out[M][128] = A[M][K] @ W[K][128] ----------------

template<int K, bool A_F32, bool OUT_BF16, bool BIAS, bool SCALE>
__global__ __launch_bounds__(256) void k_gemm(const void* __restrict__ Aptr,
                                              const ushort* __restrict__ Wt,
                                              const float* __restrict__ bias,
                                              const float* __restrict__ rowscale,
                                              void* __restrict__ Outp, int M){
  __shared__ __align__(16) ushort lA[64*32];    // [row][k]
  __shared__ __align__(16) ushort lB[128*32];   // [n][k]
  int tid  = threadIdx.x;
  int wave = tid >> 6, lane = tid & 63;
  int kg   = lane >> 4, lr = lane & 15;
  int m0   = blockIdx.x * 64;

  f32x4 acc[8];
  #pragma unroll
  for (int i = 0; i < 8; i++) acc[i] = f32x4{0.f, 0.f, 0.f, 0.f};

  for (int k0 = 0; k0 < K; k0 += 32){
    if (A_F32){
      const float* A = (const float*)Aptr;
      #pragma unroll
      for (int i = 0; i < 2; i++){
        int l = tid + i*256;
        int r = l >> 3, c4 = (l & 7) * 4;
        int gm = m0 + r;
        float4 v = make_float4(0.f, 0.f, 0.f, 0.f);
        if (gm < M) v = *(const float4*)(A + (size_t)gm*K + k0 + c4);
        ushort4 u; u.x = f2bf(v.x); u.y = f2bf(v.y); u.z = f2bf(v.z); u.w = f2bf(v.w);
        *(ushort4*)&lA[r*32 + c4] = u;
      }
    } else {
      const ushort* A = (const ushort*)Aptr;
      int r = tid >> 2, c8 = (tid & 3) * 8;
      int gm = m0 + r;
      int4 v = make_int4(0, 0, 0, 0);
      if (gm < M) v = *(const int4*)(A + (size_t)gm*K + k0 + c8);
      *(int4*)&lA[r*32 + c8] = v;
    }
    #pragma unroll
    for (int i = 0; i < 2; i++){
      int l = tid + i*256;
      int n = l >> 2, c8 = (l & 3) * 8;
      *(int4*)&lB[n*32 + c8] = *(const int4*)(Wt + (size_t)n*K + k0 + c8);
    }
    __syncthreads();

    short8 a = *(const short8*)&lA[(wave*16 + lr)*32 + kg*8];
    #pragma unroll
    for (int nt = 0; nt < 8; nt++){
      short8 b = *(const short8*)&lB[(nt*16 + lr)*32 + kg*8];
      acc[nt] = __builtin_amdgcn_mfma_f32_16x16x32_bf16(a, b, acc[nt], 0, 0, 0);
    }
    __syncthreads();
  }

  #pragma unroll
  for (int nt = 0; nt < 8; nt++){
    #pragma unroll
    for (int r = 0; r < 4; r++){
      int gm = m0 + wave*16 + kg*4 + r;
      int n  = nt*16 + lr;
      if (gm < M){
        float v = acc[nt][r];
        if (BIAS)  v += bias[n];
        if (SCALE) v *= rowscale[gm];
        if (OUT_BF16) ((ushort*)Outp)[(size_t)gm*HID + n] = f2bf(v);
        else          ((float*)Outp)[(size_t)gm*HID + n] = v;
      }
    }
  }
}

// ---------------- edge aggregation ----------------
// One wave per node. Each half-wave (32 lanes x uint2 = 256 B) gathers one edge row,
// so one load instruction covers 2 edges; v[4] batch = 8 edges in flight.
// hw is pre-scaled by dinv[row], packed bf16 (row = 64 uints = 128 cols).
// out[d] = dinv[d]*(sum_e hw[src_e] + hw[d]) + bias
// FUSE_POOL: atomicAdd (row * 1/cnt) into g[batch] instead of writing the row.

template<bool RELU, bool FUSE_POOL>
__global__ __launch_bounds__(256, 4) void k_agg(const uint* __restrict__ hw,
                                                const int* __restrict__ row_start,
                                                const int* __restrict__ csr_src,
                                                const float* __restrict__ dinv,
                                                const float* __restrict__ bias,
                                                uint* __restrict__ OutBf,
                                                const int* __restrict__ batch,
                                                const int* __restrict__ gstart,
                                                float* __restrict__ g){
  int wave = threadIdx.x >> 6, lane = threadIdx.x & 63;
  int node = blockIdx.x*4 + wave;          // grid = 12500 blocks exactly
  int half = lane >> 5, li = lane & 31;    // li indexes uint2 within the row
  const uint2* hw2 = (const uint2*)hw;

  float a0 = 0.f, a1 = 0.f, a2 = 0.f, a3 = 0.f;
  if (half == 0){                          // self loop (pre-scaled), half 0 only
    uint2 p = hw2[(size_t)node*32 + li];
    a0 = bf_lo(p.x); a1 = bf_hi(p.x); a2 = bf_lo(p.y); a3 = bf_hi(p.y);
  }

  int b = row_start[node], e = row_start[node+1];
  for (int j0 = b; j0 < e; j0 += 64){
    int jj = j0 + lane;
    int sl = (jj < e) ? csr_src[jj] : 0;
    int m = e - j0; if (m > 64) m = 64;
    for (int i = 0; i < m; i += 8){        // 8 edges per iteration, 4 load instrs
      uint2 v[4]; float msk[4];
      #pragma unroll
      for (int j = 0; j < 4; j++){
        int ei = i + 2*j + half;
        int s  = __shfl(sl, ei);
        bool ok = ei < m;
        msk[j] = ok ? 1.0f : 0.0f;
        int ss = ok ? s : node;            // safe address for masked lanes
        v[j] = hw2[(size_t)ss*32 + li];
      }
      #pragma unroll
      for (int j = 0; j < 4; j++){
        a0 += msk[j]*bf_lo(v[j].x); a1 += msk[j]*bf_hi(v[j].x);
        a2 += msk[j]*bf_lo(v[j].y); a3 += msk[j]*bf_hi(v[j].y);
      }
    }
  }

  // combine the two halves (lane and lane^32 hold the same 4-col group)
  a0 += __shfl(a0, lane ^ 32);
  a1 += __shfl(a1, lane ^ 32);
  a2 += __shfl(a2, lane ^ 32);
  a3 += __shfl(a3, lane ^ 32);

  if (half == 0){
    float dd = dinv[node];
    float v0 = a0*dd + bias[4*li+0];
    float v1 = a1*dd + bias[4*li+1];
    float v2 = a2*dd + bias[4*li+2];
    float v3 = a3*dd + bias[4*li+3];
    if (RELU){ v0 = fmaxf(v0,0.f); v1 = fmaxf(v1,0.f); v2 = fmaxf(v2,0.f); v3 = fmaxf(v3,0.f); }
    if (FUSE_POOL){
      int bg = batch[node];
      float cnt = (float)(gstart[bg+1] - gstart[bg]);
      float sc = 1.0f / fmaxf(cnt, 1.0f);
      atomicAdd(&g[bg*HID + 4*li+0], v0*sc);
      atomicAdd(&g[bg*HID + 4*li+1], v1*sc);
      atomicAdd(&g[bg*HID + 4*li+2], v2*sc);
      atomicAdd(&g[bg*HID + 4*li+3], v3*sc);
    } else {
      uint2 pk;
      pk.x = (uint)f2bf(v0) | ((uint)f2bf(v1) << 16);
      pk.y = (uint)f2bf(v2) | ((uint)f2bf(v3) << 16);
      ((uint2*)OutBf)[(size_t)node*32 + li] = pk;
    }
  }
}

// ---------------- head ----------------

__global__ void k_ranges(const int* __restrict__ batch, int* __restrict__ gstart, int N, int G){
  int b = blockIdx.x*blockDim.x + threadIdx.x;
  if (b > G) return;
  int lo = 0, hi = N;
  while (lo < hi){ int mid = (lo + hi) >> 1; if (batch[mid] < b) lo = mid + 1; else hi = mid; }
  gstart[b] = lo;
}

__global__ void k_head(const float* __restrict__ g, const float* __restrict__ W1,
                       const float* __restrict__ b1, const float* __restrict__ W2,
                       const float* __restrict__ b2, float* __restrict__ out){
  __shared__ float row[128];
  __shared__ float z[128];
  int b = blockIdx.x, t = threadIdx.x;
  row[t] = g[b*HID + t];
  __syncthreads();
  float a = b1[t];
  #pragma unroll 8
  for (int k = 0; k < 128; k++) a += row[k] * W1[k*128 + t];
  z[t] = fmaxf(a, 0.f);
  __syncthreads();
  if (t < 3){
    float o = b2[t];
    #pragma unroll 8
    for (int k = 0; k < 128; k++) o += z[k] * W2[k*3 + t];
    out[b*3 + t] = o;
  }
}

// ---------------- launch ----------------

extern "C" void kernel_launch(void* const* d_in, const int* in_sizes, int n_in,
                              void* d_out, int out_size, void* d_ws, size_t ws_size,
                              hipStream_t stream) {
  const float* x     = (const float*)d_in[0];
  const int*   ei    = (const int*)  d_in[1];
  const int*   batch = (const int*)  d_in[2];
  const float* W_emb = (const float*)d_in[3];
  const float* b_emb = (const float*)d_in[4];
  const float* W_c1  = (const float*)d_in[5];
  const float* b_c1  = (const float*)d_in[6];
  const float* W_c2  = (const float*)d_in[7];
  const float* b_c2  = (const float*)d_in[8];
  const float* W_l1  = (const float*)d_in[9];
  const float* b_l1  = (const float*)d_in[10];
  const float* W_l2  = (const float*)d_in[11];
  const float* b_l2  = (const float*)d_in[12];
  const int* src = ei;
  const int* dst = ei + N_EDGES;
  float* out = (float*)d_out;

  char* ws = (char*)d_ws;
  size_t off = 0;
  auto alloc = [&](size_t n) -> char* {
    off = (off + 255) & ~(size_t)255;
    char* p = ws + off; off += n; return p;
  };
  int*    deg       = (int*)   alloc((size_t)N_NODES*4);
  int*    cursor    = (int*)   alloc((size_t)N_NODES*4);
  int*    row_start = (int*)   alloc((size_t)(N_NODES+1)*4);
  float*  dinv      = (float*) alloc((size_t)N_NODES*4);
  int*    lexc      = (int*)   alloc((size_t)N_NODES*4);
  int*    bsum      = (int*)   alloc((size_t)SCAN_NB*4);
  int*    boff      = (int*)   alloc((size_t)SCAN_NB*4);
  int*    csr_src   = (int*)   alloc((size_t)N_EDGES*4);
  ushort* wt_emb    = (ushort*)alloc((size_t)768*HID*2);
  ushort* wt_c1     = (ushort*)alloc((size_t)HID*HID*2);
  ushort* wt_c2     = (ushort*)alloc((size_t)HID*HID*2);
  ushort* t1        = (ushort*)alloc((size_t)N_NODES*HID*2);
  ushort* h2        = (ushort*)alloc((size_t)N_NODES*HID*2);
  uint*   hw        = (uint*)  alloc((size_t)N_NODES*64*4);   // packed bf16 x2
  float*  g         = (float*) alloc((size_t)N_GRAPHS*HID*4);
  int*    gstart    = (int*)   alloc((size_t)(N_GRAPHS+1)*4);

  hipMemsetAsync(deg,    0, (size_t)N_NODES*4, stream);
  hipMemsetAsync(cursor, 0, (size_t)N_NODES*4, stream);
  hipMemsetAsync(g,      0, (size_t)N_GRAPHS*HID*4, stream);

  int eb = (N_EDGES + 255) / 256;
  int nb = (N_NODES + 255) / 256;
  k_count  <<<eb, 256, 0, stream>>>(dst, deg, N_EDGES);
  k_dinv   <<<nb, 256, 0, stream>>>(deg, dinv, N_NODES);
  k_scan1  <<<SCAN_NB, SCAN_BS, 0, stream>>>(deg, lexc, bsum, N_NODES);
  k_scan2  <<<1, 256, 0, stream>>>(bsum, boff, row_start);
  k_scan3  <<<nb, 256, 0, stream>>>(lexc, boff, row_start, N_NODES);
  k_scatter<<<eb, 256, 0, stream>>>(src, dst, row_start, cursor, csr_src, N_EDGES);
  k_ranges <<<1, 256, 0, stream>>>(batch, gstart, N_NODES, N_GRAPHS);

  k_wt<<<(768*HID + 255)/256, 256, 0, stream>>>(W_emb, wt_emb, 768);
  k_wt<<<(HID*HID + 255)/256, 256, 0, stream>>>(W_c1,  wt_c1,  HID);
  k_wt<<<(HID*HID + 255)/256, 256, 0, stream>>>(W_c2,  wt_c2,  HID);

  int gemm_blocks = (N_NODES + 63) / 64;
  // t1 = x @ W_emb + b_emb (bf16)
  k_gemm<768, true,  true,  true,  false><<<gemm_blocks, 256, 0, stream>>>(x,  wt_emb, b_emb, nullptr, t1, N_NODES);
  // hw = (t1 @ W_c1) * dinv[row]  (packed bf16)
  k_gemm<128, false, true,  false, true ><<<gemm_blocks, 256, 0, stream>>>(t1, wt_c1, nullptr, dinv, hw, N_NODES);
  // h2 = relu(agg(hw) + b_c1) (bf16)
  k_agg<true,  false><<<N_NODES/4, 256, 0, stream>>>(hw, row_start, csr_src, dinv, b_c1,
                                                     (uint*)h2, nullptr, nullptr, nullptr);
  // hw = (h2 @ W_c2) * dinv[row] (packed bf16)
  k_gemm<128, false, true,  false, true ><<<gemm_blocks, 256, 0, stream>>>(h2, wt_c2, nullptr, dinv, hw, N_NODES);
  // g += pooled(agg(hw) + b_c2)   (fused)
  k_agg<false, true ><<<N_NODES/4, 256, 0, stream>>>(hw, row_start, csr_src, dinv, b_c2,
                                                     nullptr, batch, gstart, g);

  k_head<<<N_GRAPHS, 128, 0, stream>>>(g, W_l1, b_l1, W_l2, b_l2, out);
}

// Round 6
// 532.001 us; speedup vs baseline: 1.2159x; 1.2159x over previous
//
#include <hip/hip_runtime.h>
#include <hip/hip_bf16.h>

#define N_NODES  50000
#define N_GRAPHS 128
#define N_EDGES  800000
#define HID      128
#define SCAN_BS  256
#define SCAN_NB  ((N_NODES + SCAN_BS - 1) / SCAN_BS)

typedef __attribute__((ext_vector_type(8))) short short8;
typedef __attribute__((ext_vector_type(4))) float f32x4;

static __device__ __forceinline__ ushort f2bf(float f){
  __hip_bfloat16 h = __float2bfloat16(f);
  return *reinterpret_cast<ushort*>(&h);
}
static __device__ __forceinline__ float bf_lo(uint pk){ return __uint_as_float(pk << 16); }
static __device__ __forceinline__ float bf_hi(uint pk){ return __uint_as_float(pk & 0xffff0000u); }

// ---------------- graph preprocessing ----------------

__global__ void k_count(const int* __restrict__ dst, int* __restrict__ deg, int E){
  int i = blockIdx.x*blockDim.x + threadIdx.x;
  if (i < E) atomicAdd(&deg[dst[i]], 1);
}

__global__ void k_dinv(const int* __restrict__ deg, float* __restrict__ dinv, int N){
  int i = blockIdx.x*blockDim.x + threadIdx.x;
  if (i < N) dinv[i] = rsqrtf((float)(deg[i] + 1));   // +1 self loop
}

__global__ void k_scan1(const int* __restrict__ deg, int* __restrict__ lexc,
                        int* __restrict__ bsum, int N){
  __shared__ int s[SCAN_BS];
  int t = threadIdx.x, i = blockIdx.x*SCAN_BS + t;
  int v = (i < N) ? deg[i] : 0;
  s[t] = v;
  __syncthreads();
  int acc = v;
  for (int d = 1; d < SCAN_BS; d <<= 1){
    int u = (t >= d) ? s[t-d] : 0;
    __syncthreads();
    acc += u; s[t] = acc;
    __syncthreads();
  }
  if (i < N) lexc[i] = acc - v;
  if (t == SCAN_BS-1) bsum[blockIdx.x] = acc;
}

__global__ void k_scan2(const int* __restrict__ bsum, int* __restrict__ boff,
                        int* __restrict__ row_start){
  __shared__ int s[SCAN_NB];
  int t = threadIdx.x;
  int v = (t < SCAN_NB) ? bsum[t] : 0;
  if (t < SCAN_NB) s[t] = v;
  __syncthreads();
  int acc = v;
  for (int d = 1; d < SCAN_NB; d <<= 1){
    int u = (t >= d && t - d < SCAN_NB) ? s[t-d] : 0;
    __syncthreads();
    if (t < SCAN_NB){ acc += u; s[t] = acc; }
    __syncthreads();
  }
  if (t < SCAN_NB) boff[t] = acc - v;
  if (t == SCAN_NB-1) row_start[N_NODES] = acc;
}

__global__ void k_scan3(const int* __restrict__ lexc, const int* __restrict__ boff,
                        int* __restrict__ row_start, int N){
  int i = blockIdx.x*blockDim.x + threadIdx.x;
  if (i < N) row_start[i] = lexc[i] + boff[i >> 8];
}

__global__ void k_scatter(const int* __restrict__ src, const int* __restrict__ dst,
                          const int* __restrict__ row_start, int* __restrict__ cursor,
                          int* __restrict__ csr_src, int E){
  int i = blockIdx.x*blockDim.x + threadIdx.x;
  if (i >= E) return;
  int d = dst[i];
  int pos = row_start[d] + atomicAdd(&cursor[d], 1);
  csr_src[pos] = src[i];
}

// transpose + bf16-convert weight: W[K][N] -> Wt[N][K]
__global__ void k_wt(const float* __restrict__ W, ushort* __restrict__ Wt, int K){
  int idx = blockIdx.x*blockDim.x + threadIdx.x;
  if (idx >= K*HID) return;
  int k = idx >> 7, n = idx & 127;
  Wt[n*K + k] = f2bf(W[idx]);
}

// ---------------- bf16 MFMA GEMM: Out[M][128] = A[M][K] @ W[K][128] ----------------

template<int K, bool A_F32, bool OUT_BF16, bool BIAS, bool SCALE>
__global__ __launch_bounds__(256) void k_gemm(const void* __restrict__ Aptr,
                                              const ushort* __restrict__ Wt,
                                              const float* __restrict__ bias,
                                              const float* __restrict__ rowscale,
                                              void* __restrict__ Outp, int M){
  __shared__ __align__(16) ushort lA[64*32];    // [row][k]
  __shared__ __align__(16) ushort lB[128*32];   // [n][k]
  int tid  = threadIdx.x;
  int wave = tid >> 6, lane = tid & 63;
  int kg   = lane >> 4, lr = lane & 15;
  int m0   = blockIdx.x * 64;

  f32x4 acc[8];
  #pragma unroll
  for (int i = 0; i < 8; i++) acc[i] = f32x4{0.f, 0.f, 0.f, 0.f};

  for (int k0 = 0; k0 < K; k0 += 32){
    if (A_F32){
      const float* A = (const float*)Aptr;
      #pragma unroll
      for (int i = 0; i < 2; i++){
        int l = tid + i*256;
        int r = l >> 3, c4 = (l & 7) * 4;
        int gm = m0 + r;
        float4 v = make_float4(0.f, 0.f, 0.f, 0.f);
        if (gm < M) v = *(const float4*)(A + (size_t)gm*K + k0 + c4);
        ushort4 u; u.x = f2bf(v.x); u.y = f2bf(v.y); u.z = f2bf(v.z); u.w = f2bf(v.w);
        *(ushort4*)&lA[r*32 + c4] = u;
      }
    } else {
      const ushort* A = (const ushort*)Aptr;
      int r = tid >> 2, c8 = (tid & 3) * 8;
      int gm = m0 + r;
      int4 v = make_int4(0, 0, 0, 0);
      if (gm < M) v = *(const int4*)(A + (size_t)gm*K + k0 + c8);
      *(int4*)&lA[r*32 + c8] = v;
    }
    #pragma unroll
    for (int i = 0; i < 2; i++){
      int l = tid + i*256;
      int n = l >> 2, c8 = (l & 3) * 8;
      *(int4*)&lB[n*32 + c8] = *(const int4*)(Wt + (size_t)n*K + k0 + c8);
    }
    __syncthreads();

    short8 a = *(const short8*)&lA[(wave*16 + lr)*32 + kg*8];
    #pragma unroll
    for (int nt = 0; nt < 8; nt++){
      short8 b = *(const short8*)&lB[(nt*16 + lr)*32 + kg*8];
      acc[nt] = __builtin_amdgcn_mfma_f32_16x16x32_bf16(a, b, acc[nt], 0, 0, 0);
    }
    __syncthreads();
  }

  #pragma unroll
  for (int nt = 0; nt < 8; nt++){
    #pragma unroll
    for (int r = 0; r < 4; r++){
      int gm = m0 + wave*16 + kg*4 + r;
      int n  = nt*16 + lr;
      if (gm < M){
        float v = acc[nt][r];
        if (BIAS)  v += bias[n];
        if (SCALE) v *= rowscale[gm];
        if (OUT_BF16) ((ushort*)Outp)[(size_t)gm*HID + n] = f2bf(v);
        else          ((float*)Outp)[(size_t)gm*HID + n] = v;
      }
    }
  }
}

// ---------------- edge aggregation ----------------
// One wave per node, full-wave row gather (64 lanes x uint = 256 B, 2 bf16 cols/lane).
// Row index comes from a WAVE-UNIFORM __shfl (readlane -> saddr loads).
// 16 independent gathers in flight per iteration; tail fully predicated
// (masked lanes gather row 0 harmlessly, contribution zeroed via mask FMA).
// hw is pre-scaled by dinv[row], packed bf16.
// out[d] = dinv[d]*(sum_e hw[src_e] + hw[d]) + bias
// FUSE_POOL: atomicAdd (row * 1/cnt) into g[batch] instead of writing the row.

template<bool RELU, bool FUSE_POOL>
__global__ __launch_bounds__(256, 4) void k_agg(const uint* __restrict__ hw,
                                                const int* __restrict__ row_start,
                                                const int* __restrict__ csr_src,
                                                const float* __restrict__ dinv,
                                                const float* __restrict__ bias,
                                                uint* __restrict__ OutBf,
                                                const int* __restrict__ batch,
                                                const int* __restrict__ gstart,
                                                float* __restrict__ g){
  int wave = threadIdx.x >> 6, lane = threadIdx.x & 63;
  int node = blockIdx.x*4 + wave;          // grid = 12500 blocks exactly
  uint pk0 = hw[(size_t)node*64 + lane];   // self loop (pre-scaled)
  float ax = bf_lo(pk0), ay = bf_hi(pk0);
  int b = row_start[node], e = row_start[node+1];
  for (int j0 = b; j0 < e; j0 += 64){
    int jj = j0 + lane;
    int sl = (jj < e) ? csr_src[jj] : 0;   // 0 is a safe row for masked slots
    int m = e - j0; if (m > 64) m = 64;
    for (int i = 0; i < m; i += 16){       // 16 gathers in flight
      uint v[16];
      #pragma unroll
      for (int j = 0; j < 16; j++){
        int s = __shfl(sl, i + j);         // uniform index -> readlane/saddr
        v[j] = hw[(size_t)s*64 + lane];
      }
      #pragma unroll
      for (int j = 0; j < 16; j++){
        float mk = (i + j < m) ? 1.0f : 0.0f;
        ax += mk * bf_lo(v[j]);
        ay += mk * bf_hi(v[j]);
      }
    }
  }
  float dd = dinv[node];
  float vx = ax*dd + bias[2*lane];
  float vy = ay*dd + bias[2*lane+1];
  if (RELU){ vx = fmaxf(vx, 0.f); vy = fmaxf(vy, 0.f); }
  if (FUSE_POOL){
    int bg = batch[node];
    float cnt = (float)(gstart[bg+1] - gstart[bg]);
    float sc = 1.0f / fmaxf(cnt, 1.0f);
    atomicAdd(&g[bg*HID + 2*lane],     vx*sc);
    atomicAdd(&g[bg*HID + 2*lane + 1], vy*sc);
  } else {
    uint pk = (uint)f2bf(vx) | ((uint)f2bf(vy) << 16);
    OutBf[(size_t)node*64 + lane] = pk;
  }
}

// ---------------- head ----------------

__global__ void k_ranges(const int* __restrict__ batch, int* __restrict__ gstart, int N, int G){
  int b = blockIdx.x*blockDim.x + threadIdx.x;
  if (b > G) return;
  int lo = 0, hi = N;
  while (lo < hi){ int mid = (lo + hi) >> 1; if (batch[mid] < b) lo = mid + 1; else hi = mid; }
  gstart[b] = lo;
}

__global__ void k_head(const float* __restrict__ g, const float* __restrict__ W1,
                       const float* __restrict__ b1, const float* __restrict__ W2,
                       const float* __restrict__ b2, float* __restrict__ out){
  __shared__ float row[128];
  __shared__ float z[128];
  int b = blockIdx.x, t = threadIdx.x;
  row[t] = g[b*HID + t];
  __syncthreads();
  float a = b1[t];
  #pragma unroll 8
  for (int k = 0; k < 128; k++) a += row[k] * W1[k*128 + t];
  z[t] = fmaxf(a, 0.f);
  __syncthreads();
  if (t < 3){
    float o = b2[t];
    #pragma unroll 8
    for (int k = 0; k < 128; k++) o += z[k] * W2[k*3 + t];
    out[b*3 + t] = o;
  }
}

// ---------------- launch ----------------

extern "C" void kernel_launch(void* const* d_in, const int* in_sizes, int n_in,
                              void* d_out, int out_size, void* d_ws, size_t ws_size,
                              hipStream_t stream) {
  const float* x     = (const float*)d_in[0];
  const int*   ei    = (const int*)  d_in[1];
  const int*   batch = (const int*)  d_in[2];
  const float* W_emb = (const float*)d_in[3];
  const float* b_emb = (const float*)d_in[4];
  const float* W_c1  = (const float*)d_in[5];
  const float* b_c1  = (const float*)d_in[6];
  const float* W_c2  = (const float*)d_in[7];
  const float* b_c2  = (const float*)d_in[8];
  const float* W_l1  = (const float*)d_in[9];
  const float* b_l1  = (const float*)d_in[10];
  const float* W_l2  = (const float*)d_in[11];
  const float* b_l2  = (const float*)d_in[12];
  const int* src = ei;
  const int* dst = ei + N_EDGES;
  float* out = (float*)d_out;

  char* ws = (char*)d_ws;
  size_t off = 0;
  auto alloc = [&](size_t n) -> char* {
    off = (off + 255) & ~(size_t)255;
    char* p = ws + off; off += n; return p;
  };
  int*    deg       = (int*)   alloc((size_t)N_NODES*4);
  int*    cursor    = (int*)   alloc((size_t)N_NODES*4);
  int*    row_start = (int*)   alloc((size_t)(N_NODES+1)*4);
  float*  dinv      = (float*) alloc((size_t)N_NODES*4);
  int*    lexc      = (int*)   alloc((size_t)N_NODES*4);
  int*    bsum      = (int*)   alloc((size_t)SCAN_NB*4);
  int*    boff      = (int*)   alloc((size_t)SCAN_NB*4);
  int*    csr_src   = (int*)   alloc((size_t)N_EDGES*4);
  ushort* wt_emb    = (ushort*)alloc((size_t)768*HID*2);
  ushort* wt_c1     = (ushort*)alloc((size_t)HID*HID*2);
  ushort* wt_c2     = (ushort*)alloc((size_t)HID*HID*2);
  ushort* t1        = (ushort*)alloc((size_t)N_NODES*HID*2);
  ushort* h2        = (ushort*)alloc((size_t)N_NODES*HID*2);
  uint*   hw        = (uint*)  alloc((size_t)N_NODES*64*4);   // packed bf16 x2
  float*  g         = (float*) alloc((size_t)N_GRAPHS*HID*4);
  int*    gstart    = (int*)   alloc((size_t)(N_GRAPHS+1)*4);

  hipMemsetAsync(deg,    0, (size_t)N_NODES*4, stream);
  hipMemsetAsync(cursor, 0, (size_t)N_NODES*4, stream);
  hipMemsetAsync(g,      0, (size_t)N_GRAPHS*HID*4, stream);

  int eb = (N_EDGES + 255) / 256;
  int nb = (N_NODES + 255) / 256;
  k_count  <<<eb, 256, 0, stream>>>(dst, deg, N_EDGES);
  k_dinv   <<<nb, 256, 0, stream>>>(deg, dinv, N_NODES);
  k_scan1  <<<SCAN_NB, SCAN_BS, 0, stream>>>(deg, lexc, bsum, N_NODES);
  k_scan2  <<<1, 256, 0, stream>>>(bsum, boff, row_start);
  k_scan3  <<<nb, 256, 0, stream>>>(lexc, boff, row_start, N_NODES);
  k_scatter<<<eb, 256, 0, stream>>>(src, dst, row_start, cursor, csr_src, N_EDGES);
  k_ranges <<<1, 256, 0, stream>>>(batch, gstart, N_NODES, N_GRAPHS);

  k_wt<<<(768*HID + 255)/256, 256, 0, stream>>>(W_emb, wt_emb, 768);
  k_wt<<<(HID*HID + 255)/256, 256, 0, stream>>>(W_c1,  wt_c1,  HID);
  k_wt<<<(HID*HID + 255)/256, 256, 0, stream>>>(W_c2,  wt_c2,  HID);

  int gemm_blocks = (N_NODES + 63) / 64;
  // t1 = x @ W_emb + b_emb (bf16)
  k_gemm<768, true,  true,  true,  false><<<gemm_blocks, 256, 0, stream>>>(x,  wt_emb, b_emb, nullptr, t1, N_NODES);
  // hw = (t1 @ W_c1) * dinv[row]  (packed bf16)
  k_gemm<128, false, true,  false, true ><<<gemm_blocks, 256, 0, stream>>>(t1, wt_c1, nullptr, dinv, hw, N_NODES);
  // h2 = relu(agg(hw) + b_c1) (bf16)
  k_agg<true,  false><<<N_NODES/4, 256, 0, stream>>>(hw, row_start, csr_src, dinv, b_c1,
                                                     (uint*)h2, nullptr, nullptr, nullptr);
  // hw = (h2 @ W_c2) * dinv[row] (packed bf16)
  k_gemm<128, false, true,  false, true ><<<gemm_blocks, 256, 0, stream>>>(h2, wt_c2, nullptr, dinv, hw, N_NODES);
  // g += pooled(agg(hw) + b_c2)   (fused)
  k_agg<false, true ><<<N_NODES/4, 256, 0, stream>>>(hw, row_start, csr_src, dinv, b_c2,
                                                     nullptr, batch, gstart, g);

  k_head<<<N_GRAPHS, 128, 0, stream>>>(g, W_l1, b_l1, W_l2, b_l2, out);
}